// Round 8
// baseline (130.535 us; speedup 1.0000x reference)
//
#include <hip/hip_runtime.h>
#include <hip/hip_bf16.h>
#include <math.h>

#define NN 2048
#define FF 256
#define HH 64

// ln(0.1/0.9): sigmoid(s) = 0.1 at s = -2.1972245773362196
#define S_BOUND -2.1972245773362196
#define WIN 1e-3f

#define NT2 64           // 64x64 grid of 32x32 tiles
#define N_UP2 2080       // NT2*(NT2+1)/2  (compute tiles, by<=bx)
#define N_LO2 2016       // NT2*(NT2-1)/2  (strict-lower zero tiles, fused)

// ---------------------------------------------------------------------------
// Kernel 1: comb = nf@Wfe.T + bfe + emb;  A = comb@W1a.T;  B = comb@W1b.T + b1
// Emulates numpy-f32/BLAS arithmetic: every output element is a sequential-K
// single-accumulator f32 FMA chain (k ascending), biases added afterward.
// DO NOT change the reduction order — it is bit-matched to the np reference.
// ---------------------------------------------------------------------------
__global__ __launch_bounds__(256, 1)
void k1_prep(const float* __restrict__ nf,   // N x F
             const float* __restrict__ emb,  // N x H
             const float* __restrict__ Wfe,  // H x F
             const float* __restrict__ bfe,  // H
             const float* __restrict__ W1,   // H x 2H
             const float* __restrict__ b1,   // H
             float* __restrict__ Af32, float* __restrict__ Bf32)
{
    __shared__ float chunk[64][129];   // +1 pad
    __shared__ float nf_lds[8][FF];
    __shared__ float comb_lds[8][HH];

    const int t = threadIdx.x;
    const int i0 = blockIdx.x * 8;
    const int h = t & 63;      // output column (lane-distinct)
    const int g = t >> 6;      // wave id -> rows g and g+4 (wave-uniform)

    // stage node_features rows (float4, coalesced): 8x256 floats
    #pragma unroll
    for (int k = 0; k < 2; ++k) {
        int e4 = t + k * 256;
        int r = e4 >> 6, c4 = e4 & 63;
        float4 v = *(const float4*)(nf + (size_t)(i0 + r) * FF + c4 * 4);
        nf_lds[r][c4 * 4 + 0] = v.x;
        nf_lds[r][c4 * 4 + 1] = v.y;
        nf_lds[r][c4 * 4 + 2] = v.z;
        nf_lds[r][c4 * 4 + 3] = v.w;
    }

    float acc0 = 0.0f, acc1 = 0.0f;
    for (int c = 0; c < 2; ++c) {
        __syncthreads();
        // stage Wfe[:, c*128:(c+1)*128] (64x128 floats, float4 coalesced)
        #pragma unroll
        for (int k = 0; k < 8; ++k) {
            int e4 = t + k * 256;
            int r = e4 >> 5, c4 = e4 & 31;
            float4 v = *(const float4*)(Wfe + (size_t)r * FF + c * 128 + c4 * 4);
            chunk[r][c4 * 4 + 0] = v.x;
            chunk[r][c4 * 4 + 1] = v.y;
            chunk[r][c4 * 4 + 2] = v.z;
            chunk[r][c4 * 4 + 3] = v.w;
        }
        __syncthreads();
        const float* w_row = &chunk[h][0];
        const float* nf0 = &nf_lds[g][c * 128];
        const float* nf1 = &nf_lds[g + 4][c * 128];
        // STRICT sequential f ascending, single accumulator, f32 FMA (= sgemm)
        #pragma unroll 16
        for (int f = 0; f < 128; ++f) {
            float wv = w_row[f];
            acc0 = fmaf(wv, nf0[f], acc0);
            acc1 = fmaf(wv, nf1[f], acc1);
        }
    }
    float bb = bfe[h];
    acc0 = __fadd_rn(__fadd_rn(acc0, bb), emb[(size_t)(i0 + g) * HH + h]);
    acc1 = __fadd_rn(__fadd_rn(acc1, bb), emb[(size_t)(i0 + g + 4) * HH + h]);
    comb_lds[g][h] = acc0;
    comb_lds[g + 4][h] = acc1;
    __syncthreads();

    // stage W1 (64 x 128 floats, flat float4)
    #pragma unroll
    for (int k = 0; k < 8; ++k) {
        int e4 = t + k * 256;
        float4 v = *(const float4*)(W1 + (size_t)e4 * 4);
        int r = e4 >> 5, c4 = e4 & 31;
        chunk[r][c4 * 4 + 0] = v.x;
        chunk[r][c4 * 4 + 1] = v.y;
        chunk[r][c4 * 4 + 2] = v.z;
        chunk[r][c4 * 4 + 3] = v.w;
    }
    __syncthreads();

    float a0 = 0.f, a1 = 0.f, q0 = 0.f, q1 = 0.f;
    // STRICT sequential k ascending, single accumulator per output, f32 FMA
    #pragma unroll 8
    for (int k = 0; k < HH; ++k) {
        float wa = chunk[h][k];        // W1a[h][k]
        float wb = chunk[h][64 + k];   // W1b[h][k]
        float c0 = comb_lds[g][k];     // wave-uniform broadcast
        float c1 = comb_lds[g + 4][k];
        a0 = fmaf(wa, c0, a0);  a1 = fmaf(wa, c1, a1);
        q0 = fmaf(wb, c0, q0);  q1 = fmaf(wb, c1, q1);
    }
    float b1v = b1[h];
    q0 = __fadd_rn(q0, b1v);
    q1 = __fadd_rn(q1, b1v);

    size_t o0 = (size_t)(i0 + g) * HH + h;
    size_t o1 = (size_t)(i0 + g + 4) * HH + h;
    Af32[o0] = a0;  Af32[o1] = a1;
    Bf32[o0] = q0;  Bf32[o1] = q1;
}

// ---------------------------------------------------------------------------
// Boundary recompute: numpy-einsum's exact f32 SSE order (4 strided lane
// accumulators, mul+add no-fma, tree combine), then fp64 sigmoid.
// noinline: rare path (~1e-4 of pairs), keep out of the hot loop's icache.
// ---------------------------------------------------------------------------
__device__ __attribute__((noinline))
float boundary_w(const float* __restrict__ Ai, const float* __restrict__ Bj,
                 const float* __restrict__ W2, float b2f)
{
    float l0 = 0.f, l1 = 0.f, l2 = 0.f, l3 = 0.f;
    for (int hh = 0; hh < HH; hh += 4) {
        float t0 = fmaxf(__fadd_rn(Ai[hh + 0], Bj[hh + 0]), 0.0f);
        float t1 = fmaxf(__fadd_rn(Ai[hh + 1], Bj[hh + 1]), 0.0f);
        float t2 = fmaxf(__fadd_rn(Ai[hh + 2], Bj[hh + 2]), 0.0f);
        float t3 = fmaxf(__fadd_rn(Ai[hh + 3], Bj[hh + 3]), 0.0f);
        l0 = __fadd_rn(l0, __fmul_rn(t0, W2[hh + 0]));
        l1 = __fadd_rn(l1, __fmul_rn(t1, W2[hh + 1]));
        l2 = __fadd_rn(l2, __fmul_rn(t2, W2[hh + 2]));
        l3 = __fadd_rn(l3, __fmul_rn(t3, W2[hh + 3]));
    }
    float sx = __fadd_rn(__fadd_rn(l0, l1), __fadd_rn(l2, l3));
    sx = __fadd_rn(sx, b2f);
    double w64 = 1.0 / (1.0 + exp(-(double)sx));
    return (float)w64;
}

// ---------------------------------------------------------------------------
// Kernel 2: 32x32 tiles, 2080 blocks (one per upper-triangle tile), 8
// blocks/CU (LDS 18.7 KB). Block b:
//   (1) if b < 2016: zero-fill strict-lower tile b (fire-and-forget stores
//       issued first; they drain under staging+compute);
//   (2) compute upper tile b. Per thread: i-row it=t>>3, j-quad jt=t&7 ->
//       4 outputs, 4 independent h-chains. Per-output numerics bit-identical
//       to the verified round-2..7 chain (ascending h, single acc,
//       __fadd_rn -> fmaxf -> fmaf).
// ---------------------------------------------------------------------------
__global__ __launch_bounds__(256, 8)
void k2_pairs(const float* __restrict__ Af32, const float* __restrict__ Bf32,
              const float* __restrict__ W2, const float* __restrict__ b2,
              float* __restrict__ ew, float* __restrict__ mk)
{
    __shared__ float Asl[64][36];   // [h][i], 9216 B (pad 36: float4-aligned)
    __shared__ float Bsl[64][36];   // [h][j], 9216 B
    __shared__ float W2s[64];

    const int t = threadIdx.x;
    const int b = blockIdx.x;
    const int it = t >> 3;   // i row   (0..31)
    const int jt = t & 7;    // j quad  (0..7) -> 8 lanes/row, 128B spans

    // --- fused zero-fill of one strict-lower tile (blocks 0..2015) ---
    if (b < N_LO2) {
        int z = b;
        int zby = (int)((1.0f + sqrtf((float)(1 + 8 * z))) * 0.5f);
        while (zby * (zby - 1) / 2 > z) --zby;
        while ((zby + 1) * zby / 2 <= z) ++zby;
        int zbx = z - zby * (zby - 1) / 2;
        const float4 zf = make_float4(0.f, 0.f, 0.f, 0.f);
        size_t o = (size_t)(zby * 32 + it) * NN + (zbx * 32 + jt * 4);
        *(float4*)(ew + o) = zf;
        *(float4*)(mk + o) = zf;
    }

    // --- compute-tile decode: b -> (by, bx), by<=bx over 64 rows;
    //     row by starts at by*(129-by)/2
    int by = (int)((129.0f - sqrtf((float)(16641 - 8 * b))) * 0.5f);
    while (by * (129 - by) / 2 > b) --by;
    while ((by + 1) * (128 - by) / 2 <= b) ++by;
    int bx = by + (b - by * (129 - by) / 2);
    const int i0 = by * 32, j0 = bx * 32;

    // --- stage A tile (32 x 64 f32) transposed into Asl[h][i] ---
    #pragma unroll
    for (int k = 0; k < 2; ++k) {
        int e4 = t + k * 256;
        int r = e4 >> 4, h4 = e4 & 15;
        float4 v = *(const float4*)(Af32 + (size_t)(i0 + r) * HH + h4 * 4);
        Asl[h4 * 4 + 0][r] = v.x;
        Asl[h4 * 4 + 1][r] = v.y;
        Asl[h4 * 4 + 2][r] = v.z;
        Asl[h4 * 4 + 3][r] = v.w;
    }
    // --- stage B tile (32 x 64 f32) transposed into Bsl[h][j] ---
    #pragma unroll
    for (int k = 0; k < 2; ++k) {
        int e4 = t + k * 256;
        int r = e4 >> 4, h4 = e4 & 15;
        float4 v = *(const float4*)(Bf32 + (size_t)(j0 + r) * HH + h4 * 4);
        Bsl[h4 * 4 + 0][r] = v.x;
        Bsl[h4 * 4 + 1][r] = v.y;
        Bsl[h4 * 4 + 2][r] = v.z;
        Bsl[h4 * 4 + 3][r] = v.w;
    }
    if (t < 64) W2s[t] = W2[t];
    const float b2f = b2[0];
    __syncthreads();

    float acc0 = 0.f, acc1 = 0.f, acc2 = 0.f, acc3 = 0.f;

    // STRICT ascending h, one accumulator per output, add -> max -> fma:
    // bit-identical to the verified chain.
    #pragma unroll 8
    for (int h = 0; h < HH; ++h) {
        const float w2 = W2s[h];
        const float a  = Asl[h][it];                       // 8-lane broadcast
        const float4 bv = *(const float4*)(&Bsl[h][jt * 4]);
        acc0 = fmaf(fmaxf(__fadd_rn(a, bv.x), 0.0f), w2, acc0);
        acc1 = fmaf(fmaxf(__fadd_rn(a, bv.y), 0.0f), w2, acc1);
        acc2 = fmaf(fmaxf(__fadd_rn(a, bv.z), 0.0f), w2, acc2);
        acc3 = fmaf(fmaxf(__fadd_rn(a, bv.w), 0.0f), w2, acc3);
    }

    const int gi = i0 + it;
    float sv[4] = {acc0, acc1, acc2, acc3};
    float wv[4], mv[4];
    #pragma unroll
    for (int f = 0; f < 4; ++f) {
        const int gj = j0 + jt * 4 + f;
        float s = sv[f] + b2f;
        float w; bool m;
        if (__builtin_expect(gi < gj && fabsf(s - (float)S_BOUND) < WIN, 0)) {
            w = boundary_w(Af32 + (size_t)gi * HH, Bf32 + (size_t)gj * HH,
                           W2, b2f);
            m = w > 0.1f;
        } else {
            w = 1.0f / (1.0f + __expf(-s));
            m = w > 0.1f;
        }
        const bool mm = (gi < gj) && m;
        wv[f] = mm ? w : 0.0f;
        mv[f] = mm ? 1.0f : 0.0f;
    }
    size_t o = (size_t)gi * NN + (j0 + jt * 4);
    *(float4*)(ew + o) = make_float4(wv[0], wv[1], wv[2], wv[3]);
    *(float4*)(mk + o) = make_float4(mv[0], mv[1], mv[2], mv[3]);
}

extern "C" void kernel_launch(void* const* d_in, const int* in_sizes, int n_in,
                              void* d_out, int out_size, void* d_ws, size_t ws_size,
                              hipStream_t stream)
{
    const float* nf  = (const float*)d_in[0];
    const float* emb = (const float*)d_in[1];
    const float* Wfe = (const float*)d_in[2];
    const float* bfe = (const float*)d_in[3];
    const float* W1  = (const float*)d_in[4];
    const float* b1  = (const float*)d_in[5];
    const float* W2  = (const float*)d_in[6];
    const float* b2  = (const float*)d_in[7];

    float* Af32 = (float*)d_ws;                     // N*H floats (512 KB)
    float* Bf32 = Af32 + (size_t)NN * HH;           // N*H floats (512 KB)

    float* ew = (float*)d_out;                      // edge_weights (N*N)
    float* mk = ew + (size_t)NN * NN;               // mask as 0/1 float (N*N)

    k1_prep<<<dim3(NN / 8), dim3(256), 0, stream>>>(
        nf, emb, Wfe, bfe, W1, b1, Af32, Bf32);
    k2_pairs<<<dim3(N_UP2), dim3(256), 0, stream>>>(
        Af32, Bf32, W2, b2, ew, mk);
}

// Round 9
// 104.884 us; speedup vs baseline: 1.2446x; 1.2446x over previous
//
#include <hip/hip_runtime.h>
#include <hip/hip_bf16.h>
#include <math.h>

#define NN 2048
#define FF 256
#define HH 64

// ln(0.1/0.9): sigmoid(s) = 0.1 at s = -2.1972245773362196
#define S_BOUND -2.1972245773362196
#define WIN 1e-3f

// Tile grid: 64 i-rows (32 tall) x 32 j-cols (64 wide).
// Compute tiles: c >= r>>1  -> 1056. Strict-lower zero tiles: c < r>>1 -> 992.
#define N_UP3 1056
#define N_LO3 992

// S(R) = number of strict-lower tiles in rows < R;  T(R) = compute tiles < R.
static __device__ __forceinline__ int S_lo(int R) {
    int M = R >> 1;
    return (R & 1) ? M * M : M * (M - 1);
}
static __device__ __forceinline__ int T_up(int R) {
    return 32 * R - S_lo(R);
}

// ---------------------------------------------------------------------------
// Kernel 1: comb = nf@Wfe.T + bfe + emb;  A = comb@W1a.T;  B = comb@W1b.T + b1
// Emulates numpy-f32/BLAS arithmetic: every output element is a sequential-K
// single-accumulator f32 FMA chain (k ascending), biases added afterward.
// DO NOT change the reduction order — it is bit-matched to the np reference.
// ---------------------------------------------------------------------------
__global__ __launch_bounds__(256, 1)
void k1_prep(const float* __restrict__ nf,   // N x F
             const float* __restrict__ emb,  // N x H
             const float* __restrict__ Wfe,  // H x F
             const float* __restrict__ bfe,  // H
             const float* __restrict__ W1,   // H x 2H
             const float* __restrict__ b1,   // H
             float* __restrict__ Af32, float* __restrict__ Bf32)
{
    __shared__ float chunk[64][129];   // +1 pad
    __shared__ float nf_lds[8][FF];
    __shared__ float comb_lds[8][HH];

    const int t = threadIdx.x;
    const int i0 = blockIdx.x * 8;
    const int h = t & 63;      // output column (lane-distinct)
    const int g = t >> 6;      // wave id -> rows g and g+4 (wave-uniform)

    // stage node_features rows (float4, coalesced): 8x256 floats
    #pragma unroll
    for (int k = 0; k < 2; ++k) {
        int e4 = t + k * 256;
        int r = e4 >> 6, c4 = e4 & 63;
        float4 v = *(const float4*)(nf + (size_t)(i0 + r) * FF + c4 * 4);
        nf_lds[r][c4 * 4 + 0] = v.x;
        nf_lds[r][c4 * 4 + 1] = v.y;
        nf_lds[r][c4 * 4 + 2] = v.z;
        nf_lds[r][c4 * 4 + 3] = v.w;
    }

    float acc0 = 0.0f, acc1 = 0.0f;
    for (int c = 0; c < 2; ++c) {
        __syncthreads();
        // stage Wfe[:, c*128:(c+1)*128] (64x128 floats, float4 coalesced)
        #pragma unroll
        for (int k = 0; k < 8; ++k) {
            int e4 = t + k * 256;
            int r = e4 >> 5, c4 = e4 & 31;
            float4 v = *(const float4*)(Wfe + (size_t)r * FF + c * 128 + c4 * 4);
            chunk[r][c4 * 4 + 0] = v.x;
            chunk[r][c4 * 4 + 1] = v.y;
            chunk[r][c4 * 4 + 2] = v.z;
            chunk[r][c4 * 4 + 3] = v.w;
        }
        __syncthreads();
        const float* w_row = &chunk[h][0];
        const float* nf0 = &nf_lds[g][c * 128];
        const float* nf1 = &nf_lds[g + 4][c * 128];
        // STRICT sequential f ascending, single accumulator, f32 FMA (= sgemm)
        #pragma unroll 16
        for (int f = 0; f < 128; ++f) {
            float wv = w_row[f];
            acc0 = fmaf(wv, nf0[f], acc0);
            acc1 = fmaf(wv, nf1[f], acc1);
        }
    }
    float bb = bfe[h];
    acc0 = __fadd_rn(__fadd_rn(acc0, bb), emb[(size_t)(i0 + g) * HH + h]);
    acc1 = __fadd_rn(__fadd_rn(acc1, bb), emb[(size_t)(i0 + g + 4) * HH + h]);
    comb_lds[g][h] = acc0;
    comb_lds[g + 4][h] = acc1;
    __syncthreads();

    // stage W1 (64 x 128 floats, flat float4)
    #pragma unroll
    for (int k = 0; k < 8; ++k) {
        int e4 = t + k * 256;
        float4 v = *(const float4*)(W1 + (size_t)e4 * 4);
        int r = e4 >> 5, c4 = e4 & 31;
        chunk[r][c4 * 4 + 0] = v.x;
        chunk[r][c4 * 4 + 1] = v.y;
        chunk[r][c4 * 4 + 2] = v.z;
        chunk[r][c4 * 4 + 3] = v.w;
    }
    __syncthreads();

    float a0 = 0.f, a1 = 0.f, q0 = 0.f, q1 = 0.f;
    // STRICT sequential k ascending, single accumulator per output, f32 FMA
    #pragma unroll 8
    for (int k = 0; k < HH; ++k) {
        float wa = chunk[h][k];        // W1a[h][k]
        float wb = chunk[h][64 + k];   // W1b[h][k]
        float c0 = comb_lds[g][k];     // wave-uniform broadcast
        float c1 = comb_lds[g + 4][k];
        a0 = fmaf(wa, c0, a0);  a1 = fmaf(wa, c1, a1);
        q0 = fmaf(wb, c0, q0);  q1 = fmaf(wb, c1, q1);
    }
    float b1v = b1[h];
    q0 = __fadd_rn(q0, b1v);
    q1 = __fadd_rn(q1, b1v);

    size_t o0 = (size_t)(i0 + g) * HH + h;
    size_t o1 = (size_t)(i0 + g + 4) * HH + h;
    Af32[o0] = a0;  Af32[o1] = a1;
    Bf32[o0] = q0;  Bf32[o1] = q1;
}

// ---------------------------------------------------------------------------
// Boundary recompute: numpy-einsum's exact f32 SSE order (4 strided lane
// accumulators, mul+add no-fma, tree combine), then fp64 sigmoid.
// noinline: rare path (~1e-4 of pairs), keep out of the hot loop's icache.
// ---------------------------------------------------------------------------
__device__ __attribute__((noinline))
float boundary_w(const float* __restrict__ Ai, const float* __restrict__ Bj,
                 const float* __restrict__ W2, float b2f)
{
    float l0 = 0.f, l1 = 0.f, l2 = 0.f, l3 = 0.f;
    for (int hh = 0; hh < HH; hh += 4) {
        float t0 = fmaxf(__fadd_rn(Ai[hh + 0], Bj[hh + 0]), 0.0f);
        float t1 = fmaxf(__fadd_rn(Ai[hh + 1], Bj[hh + 1]), 0.0f);
        float t2 = fmaxf(__fadd_rn(Ai[hh + 2], Bj[hh + 2]), 0.0f);
        float t3 = fmaxf(__fadd_rn(Ai[hh + 3], Bj[hh + 3]), 0.0f);
        l0 = __fadd_rn(l0, __fmul_rn(t0, W2[hh + 0]));
        l1 = __fadd_rn(l1, __fmul_rn(t1, W2[hh + 1]));
        l2 = __fadd_rn(l2, __fmul_rn(t2, W2[hh + 2]));
        l3 = __fadd_rn(l3, __fmul_rn(t3, W2[hh + 3]));
    }
    float sx = __fadd_rn(__fadd_rn(l0, l1), __fadd_rn(l2, l3));
    sx = __fadd_rn(sx, b2f);
    double w64 = 1.0 / (1.0 + exp(-(double)sx));
    return (float)w64;
}

// ---------------------------------------------------------------------------
// Kernel 2: 32(i) x 64(j) tiles. 1056 compute blocks (tiles with c >= r>>1);
// blocks 0..991 additionally zero-fill one strict-lower tile first
// (fire-and-forget, drains under staging+compute). Every output-row segment
// a block writes is 256 B aligned-contiguous -> no cross-block line sharing
// (round-8's 5x write amplification came from 128 B tile rows).
// Thread map: it=t>>4 (rows it, it+16), jt=t&15 (j-quad) -> per-quarter-wave
// stores span full 256 B lines. Per-output chain: ascending h, single acc,
// __fadd_rn -> fmaxf -> fmaf — bit-identical to the verified chain.
// ---------------------------------------------------------------------------
__global__ __launch_bounds__(256, 6)
void k2_pairs(const float* __restrict__ Af32, const float* __restrict__ Bf32,
              const float* __restrict__ W2, const float* __restrict__ b2,
              float* __restrict__ ew, float* __restrict__ mk)
{
    __shared__ float Asl[64][36];   // [h][i 0..31], 9216 B (row 144 B: aligned, bank-rotated)
    __shared__ float Bsl[64][68];   // [h][j 0..63], 17408 B (row 272 B)
    __shared__ float W2s[64];

    const int t = threadIdx.x;
    const int b = blockIdx.x;
    const int it = t >> 4;   // i row base (0..15); rows it and it+16
    const int jt = t & 15;   // j quad (0..15) -> 16 lanes x 16 B = 256 B rows

    // --- fused zero-fill of one strict-lower tile (blocks 0..991) ---
    if (b < N_LO3) {
        int z = b;
        int r = 2 * (int)sqrtf((float)z) + 1;
        if (r > 63) r = 63;
        while (S_lo(r) > z) --r;
        while (S_lo(r + 1) <= z) ++r;
        int c = z - S_lo(r);
        const int zi0 = r * 32, zj0 = c * 64;
        const float4 zf = make_float4(0.f, 0.f, 0.f, 0.f);
        #pragma unroll
        for (int e = 0; e < 2; ++e) {
            size_t o = (size_t)(zi0 + it + e * 16) * NN + (zj0 + jt * 4);
            *(float4*)(ew + o) = zf;
            *(float4*)(mk + o) = zf;
        }
    }

    // --- compute-tile decode: b -> (r, c), c >= r>>1 ---
    int r = (int)(64.0f - 2.0f * sqrtf(fmaxf(0.0f, 1024.0f - (float)b)));
    if (r < 0) r = 0;
    if (r > 63) r = 63;
    while (T_up(r) > b) --r;
    while (r < 63 && T_up(r + 1) <= b) ++r;
    int c = (r >> 1) + (b - T_up(r));
    const int i0 = r * 32, j0 = c * 64;

    // --- stage A tile (32 rows x 64 h) transposed into Asl[h][i] ---
    #pragma unroll
    for (int k = 0; k < 2; ++k) {
        int e4 = t + k * 256;
        int rr = e4 >> 4, h4 = e4 & 15;
        float4 v = *(const float4*)(Af32 + (size_t)(i0 + rr) * HH + h4 * 4);
        Asl[h4 * 4 + 0][rr] = v.x;
        Asl[h4 * 4 + 1][rr] = v.y;
        Asl[h4 * 4 + 2][rr] = v.z;
        Asl[h4 * 4 + 3][rr] = v.w;
    }
    // --- stage B tile (64 rows x 64 h) transposed into Bsl[h][j] ---
    #pragma unroll
    for (int k = 0; k < 4; ++k) {
        int e4 = t + k * 256;
        int rr = e4 >> 4, h4 = e4 & 15;
        float4 v = *(const float4*)(Bf32 + (size_t)(j0 + rr) * HH + h4 * 4);
        Bsl[h4 * 4 + 0][rr] = v.x;
        Bsl[h4 * 4 + 1][rr] = v.y;
        Bsl[h4 * 4 + 2][rr] = v.z;
        Bsl[h4 * 4 + 3][rr] = v.w;
    }
    if (t < 64) W2s[t] = W2[t];
    const float b2f = b2[0];
    __syncthreads();

    float ac[2][4];
    #pragma unroll
    for (int e = 0; e < 2; ++e)
        #pragma unroll
        for (int f = 0; f < 4; ++f) ac[e][f] = 0.0f;

    // STRICT ascending h, one accumulator per output, add -> max -> fma.
    #pragma unroll 8
    for (int h = 0; h < HH; ++h) {
        const float w2 = W2s[h];
        const float a0 = Asl[h][it];        // 16-lane broadcast
        const float a1 = Asl[h][it + 16];
        const float4 bv = *(const float4*)(&Bsl[h][jt * 4]);
        ac[0][0] = fmaf(fmaxf(__fadd_rn(a0, bv.x), 0.0f), w2, ac[0][0]);
        ac[0][1] = fmaf(fmaxf(__fadd_rn(a0, bv.y), 0.0f), w2, ac[0][1]);
        ac[0][2] = fmaf(fmaxf(__fadd_rn(a0, bv.z), 0.0f), w2, ac[0][2]);
        ac[0][3] = fmaf(fmaxf(__fadd_rn(a0, bv.w), 0.0f), w2, ac[0][3]);
        ac[1][0] = fmaf(fmaxf(__fadd_rn(a1, bv.x), 0.0f), w2, ac[1][0]);
        ac[1][1] = fmaf(fmaxf(__fadd_rn(a1, bv.y), 0.0f), w2, ac[1][1]);
        ac[1][2] = fmaf(fmaxf(__fadd_rn(a1, bv.z), 0.0f), w2, ac[1][2]);
        ac[1][3] = fmaf(fmaxf(__fadd_rn(a1, bv.w), 0.0f), w2, ac[1][3]);
    }

    #pragma unroll
    for (int e = 0; e < 2; ++e) {
        const int gi = i0 + it + e * 16;
        float wv[4], mv[4];
        #pragma unroll
        for (int f = 0; f < 4; ++f) {
            const int gj = j0 + jt * 4 + f;
            float s = ac[e][f] + b2f;
            float w; bool m;
            if (__builtin_expect(gi < gj && fabsf(s - (float)S_BOUND) < WIN, 0)) {
                w = boundary_w(Af32 + (size_t)gi * HH, Bf32 + (size_t)gj * HH,
                               W2, b2f);
                m = w > 0.1f;
            } else {
                w = 1.0f / (1.0f + __expf(-s));
                m = w > 0.1f;
            }
            const bool mm = (gi < gj) && m;
            wv[f] = mm ? w : 0.0f;
            mv[f] = mm ? 1.0f : 0.0f;
        }
        size_t o = (size_t)gi * NN + (j0 + jt * 4);
        *(float4*)(ew + o) = make_float4(wv[0], wv[1], wv[2], wv[3]);
        *(float4*)(mk + o) = make_float4(mv[0], mv[1], mv[2], mv[3]);
    }
}

extern "C" void kernel_launch(void* const* d_in, const int* in_sizes, int n_in,
                              void* d_out, int out_size, void* d_ws, size_t ws_size,
                              hipStream_t stream)
{
    const float* nf  = (const float*)d_in[0];
    const float* emb = (const float*)d_in[1];
    const float* Wfe = (const float*)d_in[2];
    const float* bfe = (const float*)d_in[3];
    const float* W1  = (const float*)d_in[4];
    const float* b1  = (const float*)d_in[5];
    const float* W2  = (const float*)d_in[6];
    const float* b2  = (const float*)d_in[7];

    float* Af32 = (float*)d_ws;                     // N*H floats (512 KB)
    float* Bf32 = Af32 + (size_t)NN * HH;           // N*H floats (512 KB)

    float* ew = (float*)d_out;                      // edge_weights (N*N)
    float* mk = ew + (size_t)NN * NN;               // mask as 0/1 float (N*N)

    k1_prep<<<dim3(NN / 8), dim3(256), 0, stream>>>(
        nf, emb, Wfe, bfe, W1, b1, Af32, Bf32);
    k2_pairs<<<dim3(N_UP3), dim3(256), 0, stream>>>(
        Af32, Bf32, W2, b2, ew, mk);
}

// Round 11
// 104.288 us; speedup vs baseline: 1.2517x; 1.0057x over previous
//
#include <hip/hip_runtime.h>
#include <hip/hip_bf16.h>
#include <math.h>

#define NN 2048
#define FF 256
#define HH 64

// ln(0.1/0.9): sigmoid(s) = 0.1 at s = -2.1972245773362196
#define S_BOUND -2.1972245773362196
#define WIN 1e-3f

// Tile grid: 64 i-rows (32 tall) x 32 j-cols (64 wide).
// Compute tiles: c >= r>>1  -> 1056. Strict-lower zero tiles: c < r>>1 -> 992.
#define N_UP3 1056
#define N_LO3 992

typedef float v4f __attribute__((ext_vector_type(4)));  // nt-store compatible

// S(R) = number of strict-lower tiles in rows < R;  T(R) = compute tiles < R.
static __device__ __forceinline__ int S_lo(int R) {
    int M = R >> 1;
    return (R & 1) ? M * M : M * (M - 1);
}
static __device__ __forceinline__ int T_up(int R) {
    return 32 * R - S_lo(R);
}

static __device__ __forceinline__ void nt_store4(float* p, float x, float y,
                                                 float z, float w) {
    v4f v; v.x = x; v.y = y; v.z = z; v.w = w;
    __builtin_nontemporal_store(v, (v4f*)p);
}

// ---------------------------------------------------------------------------
// Kernel 1: comb = nf@Wfe.T + bfe + emb;  A = comb@W1a.T;  B = comb@W1b.T + b1
// Emulates numpy-f32/BLAS arithmetic: every output element is a sequential-K
// single-accumulator f32 FMA chain (k ascending), biases added afterward.
// DO NOT change the reduction order — it is bit-matched to the np reference.
// ---------------------------------------------------------------------------
__global__ __launch_bounds__(256, 1)
void k1_prep(const float* __restrict__ nf,   // N x F
             const float* __restrict__ emb,  // N x H
             const float* __restrict__ Wfe,  // H x F
             const float* __restrict__ bfe,  // H
             const float* __restrict__ W1,   // H x 2H
             const float* __restrict__ b1,   // H
             float* __restrict__ Af32, float* __restrict__ Bf32)
{
    __shared__ float chunk[64][129];   // +1 pad
    __shared__ float nf_lds[8][FF];
    __shared__ float comb_lds[8][HH];

    const int t = threadIdx.x;
    const int i0 = blockIdx.x * 8;
    const int h = t & 63;      // output column (lane-distinct)
    const int g = t >> 6;      // wave id -> rows g and g+4 (wave-uniform)

    // stage node_features rows (float4, coalesced): 8x256 floats
    #pragma unroll
    for (int k = 0; k < 2; ++k) {
        int e4 = t + k * 256;
        int r = e4 >> 6, c4 = e4 & 63;
        float4 v = *(const float4*)(nf + (size_t)(i0 + r) * FF + c4 * 4);
        nf_lds[r][c4 * 4 + 0] = v.x;
        nf_lds[r][c4 * 4 + 1] = v.y;
        nf_lds[r][c4 * 4 + 2] = v.z;
        nf_lds[r][c4 * 4 + 3] = v.w;
    }

    float acc0 = 0.0f, acc1 = 0.0f;
    for (int c = 0; c < 2; ++c) {
        __syncthreads();
        // stage Wfe[:, c*128:(c+1)*128] (64x128 floats, float4 coalesced)
        #pragma unroll
        for (int k = 0; k < 8; ++k) {
            int e4 = t + k * 256;
            int r = e4 >> 5, c4 = e4 & 31;
            float4 v = *(const float4*)(Wfe + (size_t)r * FF + c * 128 + c4 * 4);
            chunk[r][c4 * 4 + 0] = v.x;
            chunk[r][c4 * 4 + 1] = v.y;
            chunk[r][c4 * 4 + 2] = v.z;
            chunk[r][c4 * 4 + 3] = v.w;
        }
        __syncthreads();
        const float* w_row = &chunk[h][0];
        const float* nf0 = &nf_lds[g][c * 128];
        const float* nf1 = &nf_lds[g + 4][c * 128];
        // STRICT sequential f ascending, single accumulator, f32 FMA (= sgemm)
        #pragma unroll 16
        for (int f = 0; f < 128; ++f) {
            float wv = w_row[f];
            acc0 = fmaf(wv, nf0[f], acc0);
            acc1 = fmaf(wv, nf1[f], acc1);
        }
    }
    float bb = bfe[h];
    acc0 = __fadd_rn(__fadd_rn(acc0, bb), emb[(size_t)(i0 + g) * HH + h]);
    acc1 = __fadd_rn(__fadd_rn(acc1, bb), emb[(size_t)(i0 + g + 4) * HH + h]);
    comb_lds[g][h] = acc0;
    comb_lds[g + 4][h] = acc1;
    __syncthreads();

    // stage W1 (64 x 128 floats, flat float4)
    #pragma unroll
    for (int k = 0; k < 8; ++k) {
        int e4 = t + k * 256;
        float4 v = *(const float4*)(W1 + (size_t)e4 * 4);
        int r = e4 >> 5, c4 = e4 & 31;
        chunk[r][c4 * 4 + 0] = v.x;
        chunk[r][c4 * 4 + 1] = v.y;
        chunk[r][c4 * 4 + 2] = v.z;
        chunk[r][c4 * 4 + 3] = v.w;
    }
    __syncthreads();

    float a0 = 0.f, a1 = 0.f, q0 = 0.f, q1 = 0.f;
    // STRICT sequential k ascending, single accumulator per output, f32 FMA
    #pragma unroll 8
    for (int k = 0; k < HH; ++k) {
        float wa = chunk[h][k];        // W1a[h][k]
        float wb = chunk[h][64 + k];   // W1b[h][k]
        float c0 = comb_lds[g][k];     // wave-uniform broadcast
        float c1 = comb_lds[g + 4][k];
        a0 = fmaf(wa, c0, a0);  a1 = fmaf(wa, c1, a1);
        q0 = fmaf(wb, c0, q0);  q1 = fmaf(wb, c1, q1);
    }
    float b1v = b1[h];
    q0 = __fadd_rn(q0, b1v);
    q1 = __fadd_rn(q1, b1v);

    size_t o0 = (size_t)(i0 + g) * HH + h;
    size_t o1 = (size_t)(i0 + g + 4) * HH + h;
    Af32[o0] = a0;  Af32[o1] = a1;
    Bf32[o0] = q0;  Bf32[o1] = q1;
}

// ---------------------------------------------------------------------------
// Boundary recompute: numpy-einsum's exact f32 SSE order (4 strided lane
// accumulators, mul+add no-fma, tree combine), then fp64 sigmoid.
// noinline: rare path (~1e-4 of pairs), keep out of the hot loop's icache.
// ---------------------------------------------------------------------------
__device__ __attribute__((noinline))
float boundary_w(const float* __restrict__ Ai, const float* __restrict__ Bj,
                 const float* __restrict__ W2, float b2f)
{
    float l0 = 0.f, l1 = 0.f, l2 = 0.f, l3 = 0.f;
    for (int hh = 0; hh < HH; hh += 4) {
        float t0 = fmaxf(__fadd_rn(Ai[hh + 0], Bj[hh + 0]), 0.0f);
        float t1 = fmaxf(__fadd_rn(Ai[hh + 1], Bj[hh + 1]), 0.0f);
        float t2 = fmaxf(__fadd_rn(Ai[hh + 2], Bj[hh + 2]), 0.0f);
        float t3 = fmaxf(__fadd_rn(Ai[hh + 3], Bj[hh + 3]), 0.0f);
        l0 = __fadd_rn(l0, __fmul_rn(t0, W2[hh + 0]));
        l1 = __fadd_rn(l1, __fmul_rn(t1, W2[hh + 1]));
        l2 = __fadd_rn(l2, __fmul_rn(t2, W2[hh + 2]));
        l3 = __fadd_rn(l3, __fmul_rn(t3, W2[hh + 3]));
    }
    float sx = __fadd_rn(__fadd_rn(l0, l1), __fadd_rn(l2, l3));
    sx = __fadd_rn(sx, b2f);
    double w64 = 1.0 / (1.0 + exp(-(double)sx));
    return (float)w64;
}

// ---------------------------------------------------------------------------
// Kernel 2: 32(i) x 64(j) tiles. 1056 compute blocks (tiles with c >= r>>1);
// blocks 0..991 additionally zero-fill one strict-lower tile AFTER their
// compute epilogue (post-barrier path: the zero stores drain at kernel end
// and never gate the staging barrier). All output stores are nontemporal:
// bypass the poison-dirtied L2, keep A/B panels resident.
// Every output-row segment a block writes is 256 B aligned-contiguous -> no
// cross-block line sharing. Per-output chain: ascending h, single acc,
// __fadd_rn -> fmaxf -> fmaf — bit-identical to the verified chain.
// ---------------------------------------------------------------------------
__global__ __launch_bounds__(256, 6)
void k2_pairs(const float* __restrict__ Af32, const float* __restrict__ Bf32,
              const float* __restrict__ W2, const float* __restrict__ b2,
              float* __restrict__ ew, float* __restrict__ mk)
{
    __shared__ float Asl[64][36];   // [h][i 0..31], 9216 B
    __shared__ float Bsl[64][68];   // [h][j 0..63], 17408 B
    __shared__ float W2s[64];

    const int t = threadIdx.x;
    const int b = blockIdx.x;
    const int it = t >> 4;   // i row base (0..15); rows it and it+16
    const int jt = t & 15;   // j quad (0..15) -> 16 lanes x 16 B = 256 B rows

    // --- compute-tile decode: b -> (r, c), c >= r>>1 ---
    int r = (int)(64.0f - 2.0f * sqrtf(fmaxf(0.0f, 1024.0f - (float)b)));
    if (r < 0) r = 0;
    if (r > 63) r = 63;
    while (T_up(r) > b) --r;
    while (r < 63 && T_up(r + 1) <= b) ++r;
    int c = (r >> 1) + (b - T_up(r));
    const int i0 = r * 32, j0 = c * 64;

    // --- stage A tile (32 rows x 64 h) transposed into Asl[h][i] ---
    #pragma unroll
    for (int k = 0; k < 2; ++k) {
        int e4 = t + k * 256;
        int rr = e4 >> 4, h4 = e4 & 15;
        float4 v = *(const float4*)(Af32 + (size_t)(i0 + rr) * HH + h4 * 4);
        Asl[h4 * 4 + 0][rr] = v.x;
        Asl[h4 * 4 + 1][rr] = v.y;
        Asl[h4 * 4 + 2][rr] = v.z;
        Asl[h4 * 4 + 3][rr] = v.w;
    }
    // --- stage B tile (64 rows x 64 h) transposed into Bsl[h][j] ---
    #pragma unroll
    for (int k = 0; k < 4; ++k) {
        int e4 = t + k * 256;
        int rr = e4 >> 4, h4 = e4 & 15;
        float4 v = *(const float4*)(Bf32 + (size_t)(j0 + rr) * HH + h4 * 4);
        Bsl[h4 * 4 + 0][rr] = v.x;
        Bsl[h4 * 4 + 1][rr] = v.y;
        Bsl[h4 * 4 + 2][rr] = v.z;
        Bsl[h4 * 4 + 3][rr] = v.w;
    }
    if (t < 64) W2s[t] = W2[t];
    const float b2f = b2[0];
    __syncthreads();

    float ac[2][4];
    #pragma unroll
    for (int e = 0; e < 2; ++e)
        #pragma unroll
        for (int f = 0; f < 4; ++f) ac[e][f] = 0.0f;

    // STRICT ascending h, one accumulator per output, add -> max -> fma.
    #pragma unroll 8
    for (int h = 0; h < HH; ++h) {
        const float w2 = W2s[h];
        const float a0 = Asl[h][it];        // 16-lane broadcast
        const float a1 = Asl[h][it + 16];
        const float4 bv = *(const float4*)(&Bsl[h][jt * 4]);
        ac[0][0] = fmaf(fmaxf(__fadd_rn(a0, bv.x), 0.0f), w2, ac[0][0]);
        ac[0][1] = fmaf(fmaxf(__fadd_rn(a0, bv.y), 0.0f), w2, ac[0][1]);
        ac[0][2] = fmaf(fmaxf(__fadd_rn(a0, bv.z), 0.0f), w2, ac[0][2]);
        ac[0][3] = fmaf(fmaxf(__fadd_rn(a0, bv.w), 0.0f), w2, ac[0][3]);
        ac[1][0] = fmaf(fmaxf(__fadd_rn(a1, bv.x), 0.0f), w2, ac[1][0]);
        ac[1][1] = fmaf(fmaxf(__fadd_rn(a1, bv.y), 0.0f), w2, ac[1][1]);
        ac[1][2] = fmaf(fmaxf(__fadd_rn(a1, bv.z), 0.0f), w2, ac[1][2]);
        ac[1][3] = fmaf(fmaxf(__fadd_rn(a1, bv.w), 0.0f), w2, ac[1][3]);
    }

    #pragma unroll
    for (int e = 0; e < 2; ++e) {
        const int gi = i0 + it + e * 16;
        float wv[4], mv[4];
        #pragma unroll
        for (int f = 0; f < 4; ++f) {
            const int gj = j0 + jt * 4 + f;
            float s = ac[e][f] + b2f;
            float w; bool m;
            if (__builtin_expect(gi < gj && fabsf(s - (float)S_BOUND) < WIN, 0)) {
                w = boundary_w(Af32 + (size_t)gi * HH, Bf32 + (size_t)gj * HH,
                               W2, b2f);
                m = w > 0.1f;
            } else {
                w = 1.0f / (1.0f + __expf(-s));
                m = w > 0.1f;
            }
            const bool mm = (gi < gj) && m;
            wv[f] = mm ? w : 0.0f;
            mv[f] = mm ? 1.0f : 0.0f;
        }
        size_t o = (size_t)gi * NN + (j0 + jt * 4);
        nt_store4(ew + o, wv[0], wv[1], wv[2], wv[3]);
        nt_store4(mk + o, mv[0], mv[1], mv[2], mv[3]);
    }

    // --- fused zero-fill of one strict-lower tile (post-compute: stores
    //     drain at kernel end, never gating the staging barrier) ---
    if (b < N_LO3) {
        int z = b;
        int zr = 2 * (int)sqrtf((float)z) + 1;
        if (zr > 63) zr = 63;
        while (S_lo(zr) > z) --zr;
        while (S_lo(zr + 1) <= z) ++zr;
        int zc = z - S_lo(zr);
        const int zi0 = zr * 32, zj0 = zc * 64;
        #pragma unroll
        for (int e = 0; e < 2; ++e) {
            size_t o = (size_t)(zi0 + it + e * 16) * NN + (zj0 + jt * 4);
            nt_store4(ew + o, 0.f, 0.f, 0.f, 0.f);
            nt_store4(mk + o, 0.f, 0.f, 0.f, 0.f);
        }
    }
}

extern "C" void kernel_launch(void* const* d_in, const int* in_sizes, int n_in,
                              void* d_out, int out_size, void* d_ws, size_t ws_size,
                              hipStream_t stream)
{
    const float* nf  = (const float*)d_in[0];
    const float* emb = (const float*)d_in[1];
    const float* Wfe = (const float*)d_in[2];
    const float* bfe = (const float*)d_in[3];
    const float* W1  = (const float*)d_in[4];
    const float* b1  = (const float*)d_in[5];
    const float* W2  = (const float*)d_in[6];
    const float* b2  = (const float*)d_in[7];

    float* Af32 = (float*)d_ws;                     // N*H floats (512 KB)
    float* Bf32 = Af32 + (size_t)NN * HH;           // N*H floats (512 KB)

    float* ew = (float*)d_out;                      // edge_weights (N*N)
    float* mk = ew + (size_t)NN * NN;               // mask as 0/1 float (N*N)

    k1_prep<<<dim3(NN / 8), dim3(256), 0, stream>>>(
        nf, emb, Wfe, bfe, W1, b1, Af32, Bf32);
    k2_pairs<<<dim3(N_UP3), dim3(256), 0, stream>>>(
        Af32, Bf32, W2, b2, ew, mk);
}